// Round 3
// baseline (40.397 us; speedup 1.0000x reference)
//
#include <hip/hip_runtime.h>
#include <hip/hip_cooperative_groups.h>

namespace cg = cooperative_groups;

#define NTOT 8192
#define NG   64
#define BT   256           // 4 waves per block
#define QN   (NTOT / 4)    // elements scanned per wave (2048)
#define CAP  160           // per-wave staging capacity (expected ~32, 160 = >20 sigma)
#define MAXM 512           // per-group capacity (expected ~128)

// One cooperative launch, one block per group.
//  Phase A (single pass): each wave scans its 2048-element quarter with
//    int4/float4 loads; 4 ballots per 256-element chunk; stable positions via
//    (earlier-lane matches over all 4 components) + (intra-lane prefix).
//    Matching scores land in per-wave LDS staging in original index order.
//  Phase B: stitch to compact s_s[0..m), all 256 threads do the m(m-1)/2
//    softplus terms.
//  Phase C: block reduce -> partial[2g]=sum, partial[2g+1]=count.
//  grid.sync(), then block 0 reduces the 64 partials and writes the mean.
__global__ __launch_bounds__(BT) void rankloss_coop(
    const float* __restrict__ score, const int* __restrict__ gid,
    float* __restrict__ partial, float* __restrict__ out)
{
  const int g    = blockIdx.x;
  const int tid  = threadIdx.x;
  const int wid  = tid >> 6;
  const int lane = tid & 63;

  __shared__ float s_stage[4][CAP];
  __shared__ float s_s[MAXM];
  __shared__ int   s_wcnt[4];
  __shared__ float s_red[4];

  // ---- Phase A: single-pass vectorized stable compaction ----
  const unsigned long long below = (1ull << lane) - 1ull;
  const int qbase = wid * QN;
  int cnt = 0;
  #pragma unroll
  for (int it = 0; it < QN / 256; ++it) {          // 8 iterations
    const int e = qbase + it * 256 + lane * 4;     // 16B-aligned
    const int4   g4 = *reinterpret_cast<const int4*>(gid + e);
    const float4 s4 = *reinterpret_cast<const float4*>(score + e);
    const unsigned long long m0 = __ballot(g4.x == g);
    const unsigned long long m1 = __ballot(g4.y == g);
    const unsigned long long m2 = __ballot(g4.z == g);
    const unsigned long long m3 = __ballot(g4.w == g);
    // element order within chunk is (lane, component); earlier elements =
    // all matches of earlier lanes (any component) + this lane's earlier comps
    int p = cnt + __popcll(m0 & below) + __popcll(m1 & below)
                + __popcll(m2 & below) + __popcll(m3 & below);
    if (g4.x == g) { if (p < CAP) s_stage[wid][p] = s4.x; ++p; }
    if (g4.y == g) { if (p < CAP) s_stage[wid][p] = s4.y; ++p; }
    if (g4.z == g) { if (p < CAP) s_stage[wid][p] = s4.z; ++p; }
    if (g4.w == g) { if (p < CAP) s_stage[wid][p] = s4.w; ++p; }
    cnt += __popcll(m0) + __popcll(m1) + __popcll(m2) + __popcll(m3);
  }
  if (lane == 0) s_wcnt[wid] = cnt;
  __syncthreads();

  const int m = s_wcnt[0] + s_wcnt[1] + s_wcnt[2] + s_wcnt[3];
  int base = 0;
  for (int w = 0; w < wid; ++w) base += s_wcnt[w];
  for (int t = lane; t < cnt; t += 64) s_s[base + t] = s_stage[wid][t];
  __syncthreads();

  // ---- Phase B: pairwise softplus over compact LDS array ----
  float sum = 0.f;
  const int rcol = tid & 3;
  for (int a = (tid >> 2); a < m; a += 64) {
    const float sa = s_s[a];
    for (int b = a + 1 + rcol; b < m; b += 4) {
      const float x = s_s[b] - sa;               // s_j - s_i, j > i
      sum += fmaxf(x, 0.f) + __logf(1.f + __expf(-fabsf(x)));
    }
  }

  // ---- Phase C: block reduce, write per-group partial ----
  for (int off = 32; off > 0; off >>= 1) sum += __shfl_down(sum, off, 64);
  if (lane == 0) s_red[wid] = sum;
  __syncthreads();
  if (tid == 0) {
    partial[2 * g]     = s_red[0] + s_red[1] + s_red[2] + s_red[3];
    partial[2 * g + 1] = 0.5f * (float)m * (float)(m - 1);
    __threadfence();
  }

  // ---- grid-wide sync, then block 0 finalizes ----
  cg::this_grid().sync();
  if (blockIdx.x == 0 && tid < 64) {
    float s = partial[2 * tid];
    float c = partial[2 * tid + 1];
    for (int off = 32; off > 0; off >>= 1) {
      s += __shfl_down(s, off, 64);
      c += __shfl_down(c, off, 64);
    }
    if (tid == 0) out[0] = s / c;
  }
}

extern "C" void kernel_launch(void* const* d_in, const int* in_sizes, int n_in,
                              void* d_out, int out_size, void* d_ws, size_t ws_size,
                              hipStream_t stream) {
  const float* score   = (const float*)d_in[0];
  const int*   gid     = (const int*)d_in[1];
  float*       partial = (float*)d_ws;     // 128 floats, fully rewritten each call
  float*       outp    = (float*)d_out;

  void* args[] = { (void*)&score, (void*)&gid, (void*)&partial, (void*)&outp };
  hipLaunchCooperativeKernel((void*)rankloss_coop, dim3(NG), dim3(BT),
                             args, 0, stream);
}

// Round 4
// 15.790 us; speedup vs baseline: 2.5584x; 2.5584x over previous
//
#include <hip/hip_runtime.h>

#define NTOT 8192
#define NG   64
#define BT   256           // 4 waves per block
#define QN   (NTOT / 4)    // elements scanned per wave (2048)
#define CAP  160           // per-wave staging capacity (expected ~32, 160 = >20 sigma)
#define MAXM 512           // per-group capacity (expected ~128)

// One block per group g (64 blocks).
//  Phase A (single pass): each wave scans its 2048-element quarter with
//    int4/float4 loads; 4 ballots per 256-element chunk; stable positions via
//    (earlier-lane matches over all 4 components) + (intra-lane prefix).
//    Matching scores land in per-wave LDS staging in original index order.
//  Phase B: stitch to compact s_s[0..m), all 256 threads do the m(m-1)/2
//    softplus terms.
//  Phase C: block reduce -> partial[2g]=sum, partial[2g+1]=count.
__global__ __launch_bounds__(BT) void rankloss_grouped(
    const float* __restrict__ score, const int* __restrict__ gid,
    float* __restrict__ partial)
{
  const int g    = blockIdx.x;
  const int tid  = threadIdx.x;
  const int wid  = tid >> 6;
  const int lane = tid & 63;

  __shared__ float s_stage[4][CAP];
  __shared__ float s_s[MAXM];
  __shared__ int   s_wcnt[4];
  __shared__ float s_red[4];

  // ---- Phase A: single-pass vectorized stable compaction ----
  const unsigned long long below = (1ull << lane) - 1ull;
  const int qbase = wid * QN;
  int cnt = 0;
  #pragma unroll
  for (int it = 0; it < QN / 256; ++it) {          // 8 iterations
    const int e = qbase + it * 256 + lane * 4;     // 16B-aligned
    const int4   g4 = *reinterpret_cast<const int4*>(gid + e);
    const float4 s4 = *reinterpret_cast<const float4*>(score + e);
    const unsigned long long m0 = __ballot(g4.x == g);
    const unsigned long long m1 = __ballot(g4.y == g);
    const unsigned long long m2 = __ballot(g4.z == g);
    const unsigned long long m3 = __ballot(g4.w == g);
    // element order within chunk is (lane, component); earlier elements =
    // all matches of earlier lanes (any component) + this lane's earlier comps
    int p = cnt + __popcll(m0 & below) + __popcll(m1 & below)
                + __popcll(m2 & below) + __popcll(m3 & below);
    if (g4.x == g) { if (p < CAP) s_stage[wid][p] = s4.x; ++p; }
    if (g4.y == g) { if (p < CAP) s_stage[wid][p] = s4.y; ++p; }
    if (g4.z == g) { if (p < CAP) s_stage[wid][p] = s4.z; ++p; }
    if (g4.w == g) { if (p < CAP) s_stage[wid][p] = s4.w; ++p; }
    cnt += __popcll(m0) + __popcll(m1) + __popcll(m2) + __popcll(m3);
  }
  if (lane == 0) s_wcnt[wid] = cnt;
  __syncthreads();

  const int m = s_wcnt[0] + s_wcnt[1] + s_wcnt[2] + s_wcnt[3];
  int base = 0;
  for (int w = 0; w < wid; ++w) base += s_wcnt[w];
  for (int t = lane; t < cnt; t += 64) s_s[base + t] = s_stage[wid][t];
  __syncthreads();

  // ---- Phase B: pairwise softplus over compact LDS array ----
  float sum = 0.f;
  const int rcol = tid & 3;
  for (int a = (tid >> 2); a < m; a += 64) {
    const float sa = s_s[a];
    for (int b = a + 1 + rcol; b < m; b += 4) {
      const float x = s_s[b] - sa;               // s_j - s_i, j > i
      sum += fmaxf(x, 0.f) + __logf(1.f + __expf(-fabsf(x)));
    }
  }

  // ---- Phase C: block reduce, write per-group partial ----
  for (int off = 32; off > 0; off >>= 1) sum += __shfl_down(sum, off, 64);
  if (lane == 0) s_red[wid] = sum;
  __syncthreads();
  if (tid == 0) {
    partial[2 * g]     = s_red[0] + s_red[1] + s_red[2] + s_red[3];
    partial[2 * g + 1] = 0.5f * (float)m * (float)(m - 1);
  }
}

// 64 partials -> scalar mean; exactly one wave.
__global__ void rankloss_final(const float* __restrict__ partial, float* __restrict__ out) {
  const int lane = threadIdx.x;
  float s = partial[2 * lane];
  float c = partial[2 * lane + 1];
  for (int off = 32; off > 0; off >>= 1) {
    s += __shfl_down(s, off, 64);
    c += __shfl_down(c, off, 64);
  }
  if (lane == 0) out[0] = s / c;
}

extern "C" void kernel_launch(void* const* d_in, const int* in_sizes, int n_in,
                              void* d_out, int out_size, void* d_ws, size_t ws_size,
                              hipStream_t stream) {
  const float* score   = (const float*)d_in[0];
  const int*   gid     = (const int*)d_in[1];
  float*       partial = (float*)d_ws;   // 128 floats, fully rewritten each call

  rankloss_grouped<<<NG, BT, 0, stream>>>(score, gid, partial);
  rankloss_final<<<1, 64, 0, stream>>>(partial, (float*)d_out);
}